// Round 5
// baseline (95.882 us; speedup 1.0000x reference)
//
#include <hip/hip_runtime.h>

#define B_    16
#define CIN   64
#define COUT  128
#define H_    32
#define W_    32
#define NPB   256           // maxabs grid blocks

typedef __attribute__((ext_vector_type(4)))  int int4v;    // 16 int8 = 4 VGPRs
typedef __attribute__((ext_vector_type(16))) int int16v;   // 32x32 i8 MFMA C/D

// All-lanes max of a 256-entry array (written by maxabs), no LDS, no sync.
__device__ __forceinline__ float wave_max256(const float* __restrict__ p) {
  const int lane = threadIdx.x & 63;
  float m = fmaxf(fmaxf(p[lane], p[lane + 64]),
                  fmaxf(p[lane + 128], p[lane + 192]));
#pragma unroll
  for (int off = 32; off > 0; off >>= 1)
    m = fmaxf(m, __shfl_down(m, off, 64));
  return __shfl(m, 0, 64);
}

// ---------------------------------------------------------------------------
// Dispatch 1: per-block max|x|, max|w| -> bmx[256], bmw[256] (plain stores,
// fully written before D2 reads -> poison-safe; dispatch boundary provides
// cross-XCD visibility, as verified in the round-0 pipeline). float4 loads,
// 256 blocks = 1 per CU. Round-0 verbatim.
// ---------------------------------------------------------------------------
__global__ __launch_bounds__(256) void maxabs_kernel(
    const float4* __restrict__ x4, const float4* __restrict__ w4,
    float* __restrict__ bmx, float* __restrict__ bmw) {
  const int nw4 = COUT * CIN * 9 / 4;       // 18432
  const int tid = blockIdx.x * 256 + threadIdx.x;
  float mx = 0.0f, mw = 0.0f;
#pragma unroll
  for (int k = 0; k < 4; ++k) {             // 262144 float4 / 65536 = 4
    float4 v = x4[tid + k * 65536];
    mx = fmaxf(mx, fmaxf(fmaxf(fabsf(v.x), fabsf(v.y)),
                         fmaxf(fabsf(v.z), fabsf(v.w))));
  }
  if (tid < nw4) {
    float4 v = w4[tid];
    mw = fmaxf(mw, fmaxf(fmaxf(fabsf(v.x), fabsf(v.y)),
                         fmaxf(fabsf(v.z), fabsf(v.w))));
  }
#pragma unroll
  for (int off = 32; off > 0; off >>= 1) {
    mx = fmaxf(mx, __shfl_down(mx, off, 64));
    mw = fmaxf(mw, __shfl_down(mw, off, 64));
  }
  __shared__ float smx[4], smw[4];
  const int wid = threadIdx.x >> 6;
  if ((threadIdx.x & 63) == 0) { smx[wid] = mx; smw[wid] = mw; }
  __syncthreads();
  if (threadIdx.x == 0) {
#pragma unroll
    for (int i = 1; i < 4; ++i) { mx = fmaxf(mx, smx[i]); mw = fmaxf(mw, smw[i]); }
    bmx[blockIdx.x] = mx;
    bmw[blockIdx.x] = mw;
  }
}

// ---------------------------------------------------------------------------
// Dispatch 2: fold partials in-register (wave_max256 replaces round-3's
// contended system atomics + grid barrier; the dispatch boundary IS the
// sync), then round-3's VERIFIED phases 2+3:
//   Phase 2: threads <128 (waves 0-1): quantize this block's 32-cout slice
//            of w -> LDS qw_l (36 contiguous float4 loads/thread, static
//            repack, 9 ds_write_b128). threads >=128 (waves 2-3): quantize
//            6 halo rows of x -> LDS qx_l (OOB -> zeros).
//   Phase 3: 18 x mfma_i32_32x32x32_i8 per wave from LDS (exact i32 accum),
//            scaled epilogue.
// Exact reference semantics throughout: IEEE div by max/127, rintf
// (round-half-even), clip +-127. Redundant quant cost ~3-4 us/CU -- the
// price of deleting one dispatch (~6.7 us) + both global round-trips.
// Grid 512 = (b:16, yq:8, cq:4); LDS 31.5 KB, 2 blocks/CU.
// A: A[m=lane&31][k=(lane>>5)*16+j]; B: B[k][n=lane&31].
// D: col=lane&31 (pixel x), row=(reg&3)+8*(reg>>2)+4*(lane>>5) (cout).
// ---------------------------------------------------------------------------
__global__ __launch_bounds__(256, 2) void quantconv_kernel(
    const float* __restrict__ x, const float* __restrict__ w,
    const float* __restrict__ bmx, const float* __restrict__ bmw,
    const float* __restrict__ bias, float* __restrict__ out) {
  const int t    = threadIdx.x;
  const int bb   = blockIdx.x;
  const int lane = t & 63;
  const int wid  = t >> 6;

  __shared__ __align__(16) char qw_l[18432];  // [s:9][c32:2][kb:2][o:32][16]
  __shared__ __align__(16) char qx_l[13056];  // [r:6][c32:2][kb:2][xs:34][16]

  const int b  = bb >> 5;          // batch
  const int yq = (bb >> 2) & 7;    // y quad (rows yq*4 .. yq*4+3)
  const int cq = bb & 3;           // cout quarter (couts cq*32 .. +31)

  const float mx = wave_max256(bmx);
  const float mw = wave_max256(bmw);
  const float sx = mx / 127.0f;
  const float sw = mw / 127.0f;

  // ---------------- Phase 2: quantize block-local slices into LDS ---------
  if (t < 128) {
    // weights: thread = (o, c32, kb); 144 contiguous floats of w.
    const int o = t & 31, c32 = (t >> 5) & 1, kb = t >> 6;
    const float4* __restrict__ w4 = (const float4*)w;
    const int base4 = (((cq * 32 + o) * 64 + c32 * 32 + kb * 16) * 9) >> 2;
    int qd[36];                                 // [s:9][e4:4], static-indexed
#pragma unroll
    for (int k = 0; k < 36; ++k) {
      float4 v = w4[base4 + k];
#pragma unroll
      for (int j = 0; j < 4; ++j) {
        const int idx = 4 * k + j;              // = e*9 + s
        const int e = idx / 9, s = idx - e * 9;
        const float vv = (j == 0) ? v.x : (j == 1) ? v.y : (j == 2) ? v.z : v.w;
        float q = rintf(vv / sw);
        q = fminf(fmaxf(q, -127.0f), 127.0f);
        const unsigned byte = (unsigned)((int)q & 255) << ((e & 3) * 8);
        const int d = s * 4 + (e >> 2);
        if ((e & 3) == 0) qd[d] = (int)byte;    // first touch per dword
        else             qd[d] |= (int)byte;
      }
    }
#pragma unroll
    for (int s = 0; s < 9; ++s) {
      int4v val = {qd[s * 4], qd[s * 4 + 1], qd[s * 4 + 2], qd[s * 4 + 3]};
      *(int4v*)(qw_l + (((s * 2 + c32) * 2 + kb) * 32 + o) * 16) = val;
    }
  } else {
    // x rows yq*4-1 .. yq*4+4 (6 rows incl halo), 816 16-B chunks.
    const int t2 = t - 128;
#pragma unroll
    for (int k = 0; k < 7; ++k) {
      const int ch = t2 + k * 128;
      if (ch < 816) {
        const int r = ch / 136, rem = ch - r * 136;
        const int c32 = rem / 68, rem2 = rem - c32 * 68;
        const int kb = rem2 / 34, xs = rem2 - kb * 34;
        const int yy = yq * 4 - 1 + r;
        const int xx = xs - 1;
        unsigned d0 = 0, d1 = 0, d2 = 0, d3 = 0;
        if (yy >= 0 && yy <= 31 && xx >= 0 && xx <= 31) {
          const float* __restrict__ xp =
              x + ((size_t)((b * CIN + c32 * 32 + kb * 16) * H_ + yy) * W_) + xx;
#pragma unroll
          for (int e = 0; e < 16; ++e) {        // cin stride = H*W = 1024
            float q = rintf(xp[e * 1024] / sx);
            q = fminf(fmaxf(q, -127.0f), 127.0f);
            const unsigned byte = (unsigned)((int)q & 255) << ((e & 3) * 8);
            if (e < 4) d0 |= byte; else if (e < 8) d1 |= byte;
            else if (e < 12) d2 |= byte; else d3 |= byte;
          }
        }
        int4v val = {(int)d0, (int)d1, (int)d2, (int)d3};
        *(int4v*)(qx_l + (((r * 2 + c32) * 2 + kb) * 34 + xs) * 16) = val;
      }
    }
  }
  __syncthreads();

  // ---------------- Phase 3: INT8 MFMA conv from LDS ----------------
  // Wave wid handles row y = yq*4+wid, couts cq*32..+31, 32 pixels.
  {
    const int col = lane & 31;                 // pixel x / cout_local
    const int kb  = lane >> 5;                 // k-half within 32

    int16v acc0 = (int16v)0, acc1 = (int16v)0;

#pragma unroll
    for (int kh = 0; kh < 3; ++kh) {
      const int r = wid + kh;                  // qx_l row (yy = yq*4+wid+kh-1)
#pragma unroll
      for (int kw = 0; kw < 3; ++kw) {
        const int s = kh * 3 + kw;
#pragma unroll
        for (int c32 = 0; c32 < 2; ++c32) {
          int4v a  = *(const int4v*)(qw_l + (((s * 2 + c32) * 2 + kb) * 32 + col) * 16);
          int4v bf = *(const int4v*)(qx_l + (((r * 2 + c32) * 2 + kb) * 34 + col + kw) * 16);
          if (((s * 2 + c32) & 1) == 0)
            acc0 = __builtin_amdgcn_mfma_i32_32x32x32_i8(a, bf, acc0, 0, 0, 0);
          else
            acc1 = __builtin_amdgcn_mfma_i32_32x32x32_i8(a, bf, acc1, 0, 0, 0);
        }
      }
    }

    const float sc = sx * sw;
    const int y = yq * 4 + wid;
#pragma unroll
    for (int rg = 0; rg < 16; ++rg) {
      const int row  = (rg & 3) + 8 * (rg >> 2) + 4 * kb;
      const int cout = cq * 32 + row;
      out[((b * COUT + cout) << 10) + y * W_ + col] =
          sc * (float)(acc0[rg] + acc1[rg]) + bias[cout];
    }
  }
}

// ---------------------------------------------------------------------------
extern "C" void kernel_launch(void* const* d_in, const int* in_sizes, int n_in,
                              void* d_out, int out_size, void* d_ws, size_t ws_size,
                              hipStream_t stream) {
  const float* x    = (const float*)d_in[0];
  const float* w    = (const float*)d_in[1];
  const float* bias = (const float*)d_in[2];
  float* out = (float*)d_out;

  // ws: bmx[256] | bmw[256]. Fully written by D1 before D2 reads -> no memset.
  float* bmx = (float*)d_ws;
  float* bmw = bmx + 256;

  maxabs_kernel<<<NPB, 256, 0, stream>>>((const float4*)x, (const float4*)w,
                                         bmx, bmw);
  quantconv_kernel<<<512, 256, 0, stream>>>(x, w, bmx, bmw, bias, out);
}

// Round 6
// 68.628 us; speedup vs baseline: 1.3971x; 1.3971x over previous
//
#include <hip/hip_runtime.h>

#define B_    16
#define CIN   64
#define COUT  128
#define H_    32
#define W_    32
#define HP    34            // halo-padded spatial dim
#define XCH   136           // 16B chunks per padded qx row = 2*2*34
#define NPB   256           // maxabs grid blocks

typedef __attribute__((ext_vector_type(4)))  int int4v;    // 16 int8 = 4 VGPRs
typedef __attribute__((ext_vector_type(16))) int int16v;   // 32x32 i8 MFMA C/D

// All-lanes max of a 256-entry array (written by maxabs), no LDS, no sync.
__device__ __forceinline__ float wave_max256(const float* __restrict__ p) {
  const int lane = threadIdx.x & 63;
  float m = fmaxf(fmaxf(p[lane], p[lane + 64]),
                  fmaxf(p[lane + 128], p[lane + 192]));
#pragma unroll
  for (int off = 32; off > 0; off >>= 1)
    m = fmaxf(m, __shfl_down(m, off, 64));
  return __shfl(m, 0, 64);
}

// ---------------------------------------------------------------------------
// Stage 1: per-block max|x|, max|w| -> bmx[256], bmw[256] (plain stores, no
// init needed, poison-safe). float4 loads, 256 blocks = 1 per CU.
// Round-0 verbatim (best measured structure: 68.66 us total).
// ---------------------------------------------------------------------------
__global__ __launch_bounds__(256) void maxabs_kernel(
    const float4* __restrict__ x4, const float4* __restrict__ w4,
    float* __restrict__ bmx, float* __restrict__ bmw) {
  const int nw4 = COUT * CIN * 9 / 4;       // 18432
  const int tid = blockIdx.x * 256 + threadIdx.x;
  float mx = 0.0f, mw = 0.0f;
#pragma unroll
  for (int k = 0; k < 4; ++k) {             // 262144 float4 / 65536 = 4
    float4 v = x4[tid + k * 65536];
    mx = fmaxf(mx, fmaxf(fmaxf(fabsf(v.x), fabsf(v.y)),
                         fmaxf(fabsf(v.z), fabsf(v.w))));
  }
  if (tid < nw4) {
    float4 v = w4[tid];
    mw = fmaxf(mw, fmaxf(fmaxf(fabsf(v.x), fabsf(v.y)),
                         fmaxf(fabsf(v.z), fabsf(v.w))));
  }
#pragma unroll
  for (int off = 32; off > 0; off >>= 1) {
    mx = fmaxf(mx, __shfl_down(mx, off, 64));
    mw = fmaxf(mw, __shfl_down(mw, off, 64));
  }
  __shared__ float smx[4], smw[4];
  const int wid = threadIdx.x >> 6;
  if ((threadIdx.x & 63) == 0) { smx[wid] = mx; smw[wid] = mw; }
  __syncthreads();
  if (threadIdx.x == 0) {
#pragma unroll
    for (int i = 1; i < 4; ++i) { mx = fmaxf(mx, smx[i]); mw = fmaxf(mw, smw[i]); }
    bmx[blockIdx.x] = mx;
    bmw[blockIdx.x] = mw;
  }
}

// ---------------------------------------------------------------------------
// Stage 2 (fused): quantize exactly like the reference (IEEE div by max/127,
// rintf = round-half-even, clip +-127) and pack INT8 in i8-MFMA lane order:
//   qx: s8 [B][y:34][c32:2][kb:2][xs:34][16 cin]   (halo-padded)
//   qw: s8 [s:9][c32:2][kb:2][cout:128][16 cin]
// Blocks [0,512): one (b,y) row of x.  [512,544): zero halo rows.
// [544,832): weights.
// Round-0 structure; x-path loads upgraded from 8 scalar dwords to 2 float4
// (same arithmetic per element, fewer memory round-trips on the latency-
// bound critical path).
// ---------------------------------------------------------------------------
__global__ __launch_bounds__(256) void quant_pack_kernel(
    const float* __restrict__ x, const float* __restrict__ w,
    const float* __restrict__ bmx, const float* __restrict__ bmw,
    char* __restrict__ qx, char* __restrict__ qw) {
  __shared__ __align__(16) char lds[W_ * 80];  // [x][cin], pad 64->80 (16-aligned)
  const int t = threadIdx.x;
  const int bb = blockIdx.x;
  if (bb < 512) {
    const int b = bb >> 5, y = bb & 31;
    const float s = wave_max256(bmx) / 127.0f;
    const float4* __restrict__ x4 = (const float4*)x;
#pragma unroll
    for (int k = 0; k < 2; ++k) {
      const int u = t + k * 256;            // [0, 512) float4 units
      const int cin = u >> 3, xx4 = u & 7;  // coalesced along x
      float4 v = x4[((b * CIN + cin) * H_ + y) * (W_ / 4) + xx4];
#pragma unroll
      for (int j = 0; j < 4; ++j) {
        const float vv = (j == 0) ? v.x : (j == 1) ? v.y : (j == 2) ? v.z : v.w;
        float q = rintf(vv / s);
        q = fminf(fmaxf(q, -127.0f), 127.0f);
        lds[(xx4 * 4 + j) * 80 + cin] = (char)(int)q;
      }
    }
    __syncthreads();
    // write 136 16-B chunks: c = (c32*2+kb)*34 + xs
    char* row = qx + (size_t)(b * HP + y + 1) * (XCH * 16);
    if (t < XCH) {
      const int c32 = t / 68;
      const int r   = t - c32 * 68;
      const int kb  = r / 34;
      const int xs  = r - kb * 34;
      uint4 v; v.x = v.y = v.z = v.w = 0;
      if (xs >= 1 && xs <= 32)
        v = *(const uint4*)(&lds[(xs - 1) * 80 + c32 * 32 + kb * 16]);
      *(uint4*)(row + t * 16) = v;
    }
  } else if (bb < 544) {
    // zero halo rows: idx -> (b, yy in {0,33})
    const int idx = bb - 512;
    const int b = idx >> 1, yy = (idx & 1) ? 33 : 0;
    char* row = qx + (size_t)(b * HP + yy) * (XCH * 16);
    uint4 z; z.x = z.y = z.z = z.w = 0;
    if (t < XCH) *(uint4*)(row + t * 16) = z;
  } else {
    const int i = (bb - 544) * 256 + t;     // < 73728
    const float s = wave_max256(bmw) / 127.0f;
    float q = rintf(w[i] / s);
    q = fminf(fmaxf(q, -127.0f), 127.0f);
    // i = ((o*64 + c)*3 + kh)*3 + kw
    const int kw = i % 3; int j = i / 3;
    const int kh = j % 3; j /= 3;
    const int c = j & 63; const int o = j >> 6;
    const int sidx = kh * 3 + kw;
    const int c32 = c >> 5, kb = (c >> 4) & 1, e = c & 15;
    qw[(size_t)(((sidx * 2 + c32) * 2 + kb) * 128 + o) * 16 + e] = (char)(int)q;
  }
}

// ---------------------------------------------------------------------------
// Stage 3: conv as 32x32x32 INT8 MFMA (exact: |q|<=127, i32 accum, partials
// < 2^24). Grid 512 (32 y x 16 b), 4 waves/block (cout groups), 2 blocks/CU.
// Wave = 32 pixels (one row) x 32 couts. Per (s, c32-half): one A-load + one
// B-load (16 B/lane, contiguous 512 B per half-wave) + one MFMA -> 18 MFMA,
// 36 loads per wave. A frag: A[m=lane&31][k=(lane>>5)*16+j]; B: B[k][n=lane&31].
// D: col=lane&31 (pixel x), row=(reg&3)+8*(reg>>2)+4*(lane>>5) (cout).
// Two acc chains (exact integer sum). Round-0 verbatim.
// ---------------------------------------------------------------------------
__global__ __launch_bounds__(256, 2) void conv_mfma_kernel(
    const char* __restrict__ qx,  // [16][34][2][2][34][16]
    const char* __restrict__ qw,  // [9][2][2][128][16]
    const float* __restrict__ bmx, const float* __restrict__ bmw,
    const float* __restrict__ bias, float* __restrict__ out) {
  const int lane = threadIdx.x & 63;
  const int wv   = threadIdx.x >> 6;   // cout group
  const int col  = lane & 31;          // pixel x (B) / cout row (A)
  const int kb   = lane >> 5;          // k-half within 32
  const int y    = blockIdx.x;
  const int b    = blockIdx.y;
  const int co0  = wv * 32;

  int16v acc0 = (int16v)0, acc1 = (int16v)0;

  // qx byte offsets: ((((b*34 + y+kh)*2 + c32)*2 + kb)*34 + col+kw)*16
  const char* __restrict__ xp = qx + ((size_t)(b * HP + y) * 4 + kb) * 544 + col * 16;
  // qw byte offsets: (((s*2 + c32)*2 + kb)*128 + co0+col)*16
  const char* __restrict__ wp = qw + (kb * 128 + co0 + col) * 16;

#pragma unroll
  for (int kh = 0; kh < 3; ++kh) {
    const char* __restrict__ xr = xp + (size_t)kh * (4 * 544);
#pragma unroll
    for (int kw = 0; kw < 3; ++kw) {
      const int s = kh * 3 + kw;
#pragma unroll
      for (int c32 = 0; c32 < 2; ++c32) {
        int4v a  = *(const int4v*)(wp + (s * 2 + c32) * 4096);
        int4v bf = *(const int4v*)(xr + c32 * 1088 + kw * 16);
        if (((s * 2 + c32) & 1) == 0)
          acc0 = __builtin_amdgcn_mfma_i32_32x32x32_i8(a, bf, acc0, 0, 0, 0);
        else
          acc1 = __builtin_amdgcn_mfma_i32_32x32x32_i8(a, bf, acc1, 0, 0, 0);
      }
    }
  }

  const float mx = wave_max256(bmx);
  const float mw = wave_max256(bmw);
  const float sc = (mx / 127.0f) * (mw / 127.0f);
#pragma unroll
  for (int r = 0; r < 16; ++r) {
    const int row  = (r & 3) + 8 * (r >> 2) + 4 * kb;
    const int cout = co0 + row;
    out[((b * COUT + cout) << 10) + y * W_ + col] =
        sc * (float)(acc0[r] + acc1[r]) + bias[cout];
  }
}

// ---------------------------------------------------------------------------
extern "C" void kernel_launch(void* const* d_in, const int* in_sizes, int n_in,
                              void* d_out, int out_size, void* d_ws, size_t ws_size,
                              hipStream_t stream) {
  const float* x    = (const float*)d_in[0];
  const float* w    = (const float*)d_in[1];
  const float* bias = (const float*)d_in[2];
  float* out = (float*)d_out;

  // ws: bmx[256] | bmw[256] | qx s8 [16][34][136][16] (1.19 MB) | qw s8 (73.7 KB)
  // All ws bytes used are fully written before read -> poison-safe, no memset.
  float* bmx = (float*)d_ws;
  float* bmw = bmx + 256;
  char* qx = (char*)d_ws + 2048;
  char* qw = qx + (size_t)B_ * HP * XCH * 16;

  maxabs_kernel<<<NPB, 256, 0, stream>>>((const float4*)x, (const float4*)w,
                                         bmx, bmw);
  quant_pack_kernel<<<832, 256, 0, stream>>>(x, w, bmx, bmw, qx, qw);
  conv_mfma_kernel<<<dim3(32, 16), 256, 0, stream>>>(qx, qw, bmx, bmw, bias, out);
}